// Round 4
// baseline (131.069 us; speedup 1.0000x reference)
//
#include <hip/hip_runtime.h>

// MendGraph: pure data movement.
// Output (flat float32): [x | preds] then edges row0 [orig | generated] then row1.
//   OUT_X = (N + N*P)*D elements; E_out = E + 2*N*P elements per edge row.
// All segment boundaries divisible by 4 for the production shape
// (N=100000, P=5, D=128, E=3200000), so vec4 addressing is exact.

typedef float f32x4 __attribute__((ext_vector_type(4)));
typedef int   i32x4 __attribute__((ext_vector_type(4)));

__global__ __launch_bounds__(256) void mendgraph_fused(
    const f32x4* __restrict__ x4,
    const f32x4* __restrict__ pred4,
    const i32x4* __restrict__ edges4,
    f32x4* __restrict__ out4,
    long n4_x,      // N*D/4
    long n4_xp,     // (N*D + N*P*D)/4  (x + preds, contiguous in output)
    long n4_e,      // E/4
    long n4_new,    // N*2*P/4
    long out_x4,    // OUT_X/4
    long E_out4,    // E_out/4
    int N, int P)
{
    const long S = (long)gridDim.x * blockDim.x;
    const long g = (long)blockIdx.x * blockDim.x + threadIdx.x;
    const int twoP = 2 * P;

    // 1) [x | preds] -> out[0, (N+N*P)*D): one contiguous destination range.
    //    Per-lane source-address select, then unroll x4 for 4 loads in flight.
    {
        long t = g;
        for (; t + 3 * S < n4_xp; t += 4 * S) {
            long t0 = t, t1 = t + S, t2 = t + 2 * S, t3 = t + 3 * S;
            const f32x4* a0 = (t0 < n4_x) ? (x4 + t0) : (pred4 + (t0 - n4_x));
            const f32x4* a1 = (t1 < n4_x) ? (x4 + t1) : (pred4 + (t1 - n4_x));
            const f32x4* a2 = (t2 < n4_x) ? (x4 + t2) : (pred4 + (t2 - n4_x));
            const f32x4* a3 = (t3 < n4_x) ? (x4 + t3) : (pred4 + (t3 - n4_x));
            f32x4 v0 = __builtin_nontemporal_load(a0);
            f32x4 v1 = __builtin_nontemporal_load(a1);
            f32x4 v2 = __builtin_nontemporal_load(a2);
            f32x4 v3 = __builtin_nontemporal_load(a3);
            __builtin_nontemporal_store(v0, out4 + t0);
            __builtin_nontemporal_store(v1, out4 + t1);
            __builtin_nontemporal_store(v2, out4 + t2);
            __builtin_nontemporal_store(v3, out4 + t3);
        }
        for (; t < n4_xp; t += S) {
            const f32x4* a = (t < n4_x) ? (x4 + t) : (pred4 + (t - n4_x));
            f32x4 v = __builtin_nontemporal_load(a);
            __builtin_nontemporal_store(v, out4 + t);
        }
    }

    // 2) original edges, both rows: int -> float convert-copy
    #pragma unroll
    for (int row = 0; row < 2; ++row) {
        const i32x4* src = edges4 + (long)row * n4_e;
        f32x4*       dst = out4 + out_x4 + (long)row * E_out4;
        for (long t = g; t < n4_e; t += S) {
            i32x4 v = __builtin_nontemporal_load(src + t);
            f32x4 f;
            f.x = (float)v.x; f.y = (float)v.y; f.z = (float)v.z; f.w = (float)v.w;
            __builtin_nontemporal_store(f, dst + t);
        }
    }

    // 3) generated new-edge ids, both rows.
    //    element e: i = e/(2P), k = e%(2P)
    //    row0 val = k<P ? i : N + i*P + (k-P);  row1 val = k<P ? N + i*P + k : i
    #pragma unroll
    for (int row = 0; row < 2; ++row) {
        f32x4* dst = out4 + out_x4 + (long)row * E_out4 + n4_e;
        for (long t = g; t < n4_new; t += S) {
            long e = 4 * t;
            f32x4 f;
            #pragma unroll
            for (int q = 0; q < 4; ++q) {
                long ee = e + q;
                int i = (int)(ee / twoP);
                int k = (int)(ee - (long)i * twoP);
                int val;
                if (row == 0) val = (k < P) ? i : (N + i * P + (k - P));
                else          val = (k < P) ? (N + i * P + k) : i;
                f[q] = (float)val;
            }
            __builtin_nontemporal_store(f, dst + t);
        }
    }
}

extern "C" void kernel_launch(void* const* d_in, const int* in_sizes, int n_in,
                              void* d_out, int out_size, void* d_ws, size_t ws_size,
                              hipStream_t stream) {
    const float* x     = (const float*)d_in[0];
    const int*   edges = (const int*)d_in[1];
    const float* preds = (const float*)d_in[2];
    // d_in[3] = node_ids (arange); only N is needed.

    const long N = in_sizes[3];
    const long D = in_sizes[0] / N;               // 128
    const long P = in_sizes[2] / (N * D);         // 5
    const long E = in_sizes[1] / 2;               // 3,200,000

    const long E_out       = E + 2 * N * P;       // 4,200,000
    const long out_x_elems = (N + N * P) * D;     // 76,800,000

    const long n4_x   = (N * D) / 4;              // 3.2M
    const long n4_xp  = out_x_elems / 4;          // 19.2M
    const long n4_e   = E / 4;                    // 800K per row
    const long n4_new = (N * 2 * P) / 4;          // 250K per row

    const int block = 256;
    long blocks = 8192;
    const long total4 = n4_xp + 2 * (n4_e + n4_new);
    if (blocks > (total4 + block - 1) / block) blocks = (total4 + block - 1) / block;

    mendgraph_fused<<<(int)blocks, block, 0, stream>>>(
        (const f32x4*)x, (const f32x4*)preds, (const i32x4*)edges,
        (f32x4*)d_out, n4_x, n4_xp, n4_e, n4_new,
        out_x_elems / 4, E_out / 4, (int)N, (int)P);
}

// Round 5
// 121.007 us; speedup vs baseline: 1.0832x; 1.0832x over previous
//
#include <hip/hip_runtime.h>

// MendGraph: pure data movement.
// Output (flat float32): [x | preds] then edges row0 [orig | generated] then row1.
//   OUT_X = (N + N*P)*D elements; E_out = E + 2*N*P elements per edge row.
// Block-partitioned: blocks [0, nb_xp) copy x+preds; blocks [nb_xp, nb) do
// edge convert-copy + generated ids. All segment boundaries divisible by 4
// for the production shape (N=100000, P=5, D=128, E=3200000).

typedef float f32x4 __attribute__((ext_vector_type(4)));
typedef int   i32x4 __attribute__((ext_vector_type(4)));

__global__ __launch_bounds__(256) void mendgraph_part(
    const f32x4* __restrict__ x4,
    const f32x4* __restrict__ pred4,
    const i32x4* __restrict__ edges4,
    f32x4* __restrict__ out4,
    long n4_x,      // N*D/4
    long n4_p,      // N*P*D/4
    long n4_e,      // E/4
    long n4_new,    // N*2*P/4
    long out_x4,    // OUT_X/4
    long E_out4,    // E_out/4
    int  nb_xp,     // blocks assigned to the x/preds copy
    int N, int P)
{
    const int b = blockIdx.x;

    if (b < nb_xp) {
        // ---- partition A: [x | preds] -> out[0, OUT_X) ----
        const long S = (long)nb_xp * blockDim.x;
        const long g = (long)b * blockDim.x + threadIdx.x;
        for (long t = g; t < n4_x; t += S) {
            f32x4 v = __builtin_nontemporal_load(x4 + t);
            __builtin_nontemporal_store(v, out4 + t);
        }
        f32x4* outp = out4 + n4_x;
        for (long t = g; t < n4_p; t += S) {
            f32x4 v = __builtin_nontemporal_load(pred4 + t);
            __builtin_nontemporal_store(v, outp + t);
        }
    } else {
        // ---- partition B: edges convert-copy + generated ids ----
        const int  nb_e = gridDim.x - nb_xp;
        const long S = (long)nb_e * blockDim.x;
        const long g = (long)(b - nb_xp) * blockDim.x + threadIdx.x;
        const int twoP = 2 * P;

        #pragma unroll
        for (int row = 0; row < 2; ++row) {
            const i32x4* src = edges4 + (long)row * n4_e;
            f32x4*       dst = out4 + out_x4 + (long)row * E_out4;
            for (long t = g; t < n4_e; t += S) {
                i32x4 v = __builtin_nontemporal_load(src + t);
                f32x4 f;
                f.x = (float)v.x; f.y = (float)v.y; f.z = (float)v.z; f.w = (float)v.w;
                __builtin_nontemporal_store(f, dst + t);
            }
        }

        // generated new-edge ids:
        //   element e: i = e/(2P), k = e%(2P)
        //   row0 val = k<P ? i : N + i*P + (k-P);  row1 val = k<P ? N + i*P + k : i
        #pragma unroll
        for (int row = 0; row < 2; ++row) {
            f32x4* dst = out4 + out_x4 + (long)row * E_out4 + n4_e;
            for (long t = g; t < n4_new; t += S) {
                long e = 4 * t;
                f32x4 f;
                #pragma unroll
                for (int q = 0; q < 4; ++q) {
                    long ee = e + q;
                    int i = (int)(ee / twoP);
                    int k = (int)(ee - (long)i * twoP);
                    int val;
                    if (row == 0) val = (k < P) ? i : (N + i * P + (k - P));
                    else          val = (k < P) ? (N + i * P + k) : i;
                    f[q] = (float)val;
                }
                __builtin_nontemporal_store(f, dst + t);
            }
        }
    }
}

extern "C" void kernel_launch(void* const* d_in, const int* in_sizes, int n_in,
                              void* d_out, int out_size, void* d_ws, size_t ws_size,
                              hipStream_t stream) {
    const float* x     = (const float*)d_in[0];
    const int*   edges = (const int*)d_in[1];
    const float* preds = (const float*)d_in[2];
    // d_in[3] = node_ids (arange); only N is needed.

    const long N = in_sizes[3];
    const long D = in_sizes[0] / N;               // 128
    const long P = in_sizes[2] / (N * D);         // 5
    const long E = in_sizes[1] / 2;               // 3,200,000

    const long E_out       = E + 2 * N * P;       // 4,200,000
    const long out_x_elems = (N + N * P) * D;     // 76,800,000

    const long n4_x   = (N * D) / 4;              // 3.2M
    const long n4_p   = (N * P * D) / 4;          // 16M
    const long n4_e   = E / 4;                    // 800K per row
    const long n4_new = (N * 2 * P) / 4;          // 250K per row

    const int block  = 256;
    const int blocks = 4096;
    // Split blocks proportionally to bytes moved:
    //   A = x+preds = 19.2M vec4; B = edges+new = 2*(800K+250K) = 2.1M vec4
    const long tA = n4_x + n4_p;
    const long tB = 2 * (n4_e + n4_new);
    int nb_xp = (int)((tA * blocks) / (tA + tB));   // ~3690
    if (nb_xp < 1) nb_xp = 1;
    if (nb_xp > blocks - 1) nb_xp = blocks - 1;

    mendgraph_part<<<blocks, block, 0, stream>>>(
        (const f32x4*)x, (const f32x4*)preds, (const i32x4*)edges,
        (f32x4*)d_out, n4_x, n4_p, n4_e, n4_new,
        out_x_elems / 4, E_out / 4, nb_xp, (int)N, (int)P);
}